// Round 12
// baseline (171.983 us; speedup 1.0000x reference)
//
#include <hip/hip_runtime.h>
#include <cstdint>

// VectorQuantizer: x[16,1024,16,16] f32, codebook[1,8192,1024], values[1,8192,1024]
// Round 19 (r17 HW: passed, absmax 0.0, total 170.9 us, dist 44.4 us; tail has
// been ~128 us flat across 3 tail rewrites -> ~75-85 us is launch/fixed
// overhead, not kernel bodies). This round: fuse gather INTO selres
// ("selgather"): the block's 8 waves own 8 CONSECUTIVE tokens (same b,
// consecutive n), so after fidx is known the block cooperatively writes
// out[b][d][n0..n0+7] -- 32B contiguous per thread, values reads stay fully
// coalesced. Kills one launch + the fidx global round-trip. dist/prep/transx:
// byte-identical to HW-verified r17 build.

constexpr int Dd = 1024;   // feature dim (GEMM K)
constexpr int Nn = 256;    // tokens per batch
constexpr int Bb = 16;     // batch
constexpr int Kk = 8192;   // codes (GEMM N)
constexpr int Mm = 4096;   // tokens (GEMM M)
constexpr int STAGES = Dd / 64;     // 16 x 64B K-chunks (kb index)
constexpr int NITER = STAGES / 2;   // 8 main-loop iterations, 128B K per iter
constexpr int NCHUNK = Kk / 64;     // 128 chunks of 64 codes
constexpr int NCAND = NCHUNK * 2;   // 256 candidates per token
constexpr float QS = 24.0f;         // quant scale
constexpr float SC2 = 2.0f / (QS * QS);

typedef __attribute__((ext_vector_type(4))) int vi4;       // 16 i8 = 4 VGPRs
typedef unsigned long long u64;
typedef unsigned char uchar;

__device__ __forceinline__ void gload16(const void* g, void* l) {
    // async global->LDS; lds dest = wave-uniform base + lane*16 (verified r2-r5)
    __builtin_amdgcn_global_load_lds((const __attribute__((address_space(1))) uint32_t*)g,
                                     (__attribute__((address_space(3))) uint32_t*)l, 16, 0, 0);
}

// DPP row_ror:N within 16-lane rows (VALU-rate cross-lane; all lanes active).
template <int CTRL>
__device__ __forceinline__ uint32_t rot16(uint32_t v) {
    return (uint32_t)__builtin_amdgcn_update_dpp(0, (int)v, CTRL, 0xF, 0xF, true);
}
template <int CTRL>
__device__ __forceinline__ u64 rot16_64(u64 v) {
    uint32_t lo = rot16<CTRL>((uint32_t)v);
    uint32_t hi = rot16<CTRL>((uint32_t)(v >> 32));
    return ((u64)hi << 32) | lo;
}

__device__ __forceinline__ void mm2u(uint32_t& a, uint32_t& b) {  // sort pair asc
    uint32_t lo = a < b ? a : b;
    uint32_t hi = a < b ? b : a;
    a = lo; b = hi;
}
// merge sorted pairs: (a1,a2) <- top-2 (smallest) of {a1,a2,b1,b2}
__device__ __forceinline__ void merge2u(uint32_t& a1, uint32_t& a2, uint32_t b1,
                                        uint32_t b2) {
    uint32_t t1 = a1 < b1 ? a1 : b1;
    uint32_t hi = a1 < b1 ? b1 : a1;
    uint32_t l2 = a2 < b2 ? a2 : b2;
    a2 = hi < l2 ? hi : l2;
    a1 = t1;
}

__device__ __forceinline__ int q8(float v) {  // round-to-nearest, clamp [-127,127]
    int qi = (int)rintf(v * QS);
    qi = qi > 127 ? 127 : (qi < -127 ? -127 : qi);
    return qi & 0xFF;
}
__device__ __forceinline__ int pk4i(float a, float b, float c, float d) {
    return q8(a) | (q8(b) << 8) | (q8(c) << 16) | (q8(d) << 24);
}

// Fragment-order packed layout (A and B identical; verified-symmetric for the
// 16x16 family): P[(g*16 + kb)*64 + lane]*16B, g = row>>4, kb = k>>6,
// lane = (row&15) | (q<<4), q = (k>>4)&3, byte j = k&15.

// ---------- prep ----------
// grid 1024: [0,512) cb->Bpk + esq; [512,1024) x->Apk (+xT when non-null)
__global__ __launch_bounds__(256) void prep_kernel(const float* __restrict__ x,
                                                   const float* __restrict__ cb,
                                                   uchar* __restrict__ Apk,
                                                   uchar* __restrict__ Bpk,
                                                   float* __restrict__ esq,
                                                   float* __restrict__ xT) {
    const int tid = threadIdx.x;
    if (blockIdx.x < 512) {  // codebook: 16 codes/block; thread=(rl 4b hi, seg 4b lo)
        const int rl = tid >> 4, seg = tid & 15;   // seg == kb
        const int code = blockIdx.x * 16 + rl;
        const float* src = cb + (size_t)code * Dd + seg * 64;
        float v[64];
        float ss = 0.f;
#pragma unroll
        for (int j = 0; j < 64; j += 4) {
            float4 f = *(const float4*)&src[j];
            v[j] = f.x; v[j + 1] = f.y; v[j + 2] = f.z; v[j + 3] = f.w;
            ss += f.x * f.x + f.y * f.y + f.z * f.z + f.w * f.w;
        }
#pragma unroll
        for (int off = 8; off; off >>= 1) ss += __shfl_down(ss, off, 16);
        if (seg == 0) esq[code] = ss;
        const int g = code >> 4, rlane = code & 15;
#pragma unroll
        for (int q = 0; q < 4; ++q) {
            int o[4];
#pragma unroll
            for (int w4 = 0; w4 < 4; ++w4) {
                const int j = q * 16 + w4 * 4;
                o[w4] = pk4i(v[j], v[j + 1], v[j + 2], v[j + 3]);
            }
            *(uint4*)&Bpk[((size_t)(g * 16 + seg) * 64 + (rlane | (q << 4))) * 16] =
                *(const uint4*)o;
        }
    } else {  // x -> Apk (+ xT): block=(b, d-chunk of 32), thread=n
        const int bb = blockIdx.x - 512;
        const int b = bb >> 5, d0 = (bb & 31) * 32, n = tid;
        const int t = b * 256 + n;
        const float* xb = x + (size_t)b * Dd * Nn + n;
        const int g = t >> 4, rlane = t & 15, kb = d0 >> 6, qbase = (d0 & 32) >> 4;
        float v[32];
#pragma unroll
        for (int jj = 0; jj < 32; ++jj) v[jj] = xb[(size_t)(d0 + jj) * Nn];
#pragma unroll
        for (int h = 0; h < 2; ++h) {
            int o[4];
#pragma unroll
            for (int w4 = 0; w4 < 4; ++w4) {
                const int j = h * 16 + w4 * 4;
                o[w4] = pk4i(v[j], v[j + 1], v[j + 2], v[j + 3]);
            }
            *(uint4*)&Apk[((size_t)(g * 16 + kb) * 64 + (rlane | ((qbase + h) << 4))) * 16] =
                *(const uint4*)o;
        }
        if (xT) {  // bigws only: write the already-loaded slice to xT
            float* row = xT + (size_t)t * Dd + d0;
#pragma unroll
            for (int jj = 0; jj < 32; jj += 4) {
                float4 f;
                f.x = v[jj]; f.y = v[jj + 1]; f.z = v[jj + 2]; f.w = v[jj + 3];
                *(float4*)&row[jj] = f;
            }
        }
    }
}

// ---------- x -> xT fp32 (fallback path, AFTER dist; aliases Apk/Bpk region) ----------
__global__ __launch_bounds__(256) void transx_kernel(const float* __restrict__ x,
                                                     float* __restrict__ xT) {
    const int n = threadIdx.x, b = blockIdx.x, d0 = blockIdx.y * 32;
    const float* xb = x + (size_t)b * Dd * Nn + n;
    float* row = xT + (size_t)(b * Nn + n) * Dd + d0;
#pragma unroll
    for (int jj = 0; jj < 8; ++jj) {
        float4 v;
        v.x = xb[(size_t)(d0 + jj * 4 + 0) * Nn];
        v.y = xb[(size_t)(d0 + jj * 4 + 1) * Nn];
        v.z = xb[(size_t)(d0 + jj * 4 + 2) * Nn];
        v.w = xb[(size_t)(d0 + jj * 4 + 3) * Nn];
        *(float4*)&row[jj * 4] = v;
    }
}

// ---------- i8 MFMA distance: 256x256 tile, single-barrier iterations ----------
// grid (32, 16), 512 threads = 8 waves (wm in [0,2), wn in [0,4)).
// Wave owns a 128x64 output tile = 8x4 fragments of 16x16x64 MFMA.
// LDS: double buffer x 2 K-tiles(64B) x 16 groups x 1KB for A and for B = 128 KB.
// Main loop: 8 iters, 128B K each, ONE barrier per iter (HW-verified r15-r17):
//   vmcnt(0) -> s_barrier -> sched_barrier(0) -> issue 8 gloads for iter i+1 ->
//   24 ds_read_b128 + 64 MFMA, setprio(1).
__global__ __launch_bounds__(512, 2) void mfma_dist_kernel(const uchar* __restrict__ Apk,
                                                           const uchar* __restrict__ Bpk,
                                                           const float* __restrict__ esq,
                                                           u64* __restrict__ cand) {
    __shared__ uchar As[2 * 2 * 16 * 1024];  // [buf][kt][group][1KB]
    __shared__ uchar Bs[2 * 2 * 16 * 1024];

    const int tid = threadIdx.x, lane = tid & 63, w = tid >> 6;
    const int wm = w >> 2, wn = w & 3;
    const int nBase = blockIdx.x * 256, mBase = blockIdx.y * 256;
    const int gA = blockIdx.y * 16, gB = blockIdx.x * 16;  // global 16-row group bases

    vi4 acc[8][4];
#pragma unroll
    for (int i = 0; i < 8; ++i)
#pragma unroll
        for (int j = 0; j < 4; ++j) acc[i][j] = (vi4)0;

    // Staging assignment: waves 0-3 stage A groups (w&3)*4..+3, waves 4-7 stage B.
    const uchar* gmat = (w < 4) ? Apk : Bpk;
    const int gBase = ((w < 4) ? gA : gB) + (w & 3) * 4;
    const uchar* gsrc = gmat + (size_t)gBase * 16384 + (size_t)lane * 16;
    uchar* swave = ((w < 4) ? As : Bs) + (w & 3) * 4096;  // + buf*32768 + kt*16384 + r*1024

    // issue both kt sub-tiles of iteration it into buffer buf
    auto stage_iter = [&](int buf, int it) {
#pragma unroll
        for (int kt = 0; kt < 2; ++kt) {
            const int kb = 2 * it + kt;
            uchar* ldst = swave + buf * 32768 + kt * 16384;
#pragma unroll
            for (int r = 0; r < 4; ++r)
                gload16(gsrc + (size_t)(r * 16 + kb) * 1024, ldst + r * 1024);
        }
    };

    auto compute = [&](int buf, int kt) {
        const uchar* ab = As + buf * 32768 + kt * 16384;
        const uchar* bb = Bs + buf * 32768 + kt * 16384;
        vi4 af[8], bf[4];
#pragma unroll
        for (int mi = 0; mi < 8; ++mi)
            af[mi] = *(const vi4*)&ab[((wm * 8 + mi) * 64 + lane) * 16];
#pragma unroll
        for (int ni = 0; ni < 4; ++ni)
            bf[ni] = *(const vi4*)&bb[((wn * 4 + ni) * 64 + lane) * 16];
#pragma unroll
        for (int mi = 0; mi < 8; ++mi)
#pragma unroll
            for (int ni = 0; ni < 4; ++ni)
                acc[mi][ni] = __builtin_amdgcn_mfma_i32_16x16x64_i8(
                    af[mi], bf[ni], acc[mi][ni], 0, 0, 0);
    };

    // prologue: stage iter 0 into buf 0
    stage_iter(0, 0);

    for (int i = 0; i < NITER; ++i) {
        const int buf = i & 1;
        asm volatile("s_waitcnt vmcnt(0)" ::: "memory");  // iter i's loads done
        __builtin_amdgcn_s_barrier();                     // publish to all waves
        __builtin_amdgcn_sched_barrier(0);                // pin everything below
        if (i + 1 < NITER) stage_iter(buf ^ 1, i + 1);    // post-barrier: WAR-safe
        __builtin_amdgcn_s_setprio(1);
        compute(buf, 0);
        compute(buf, 1);
        __builtin_amdgcn_s_setprio(0);
    }

    // Epilogue. C/D: col = lane&15 (+ni*16), row = (lane>>4)*4 + reg.
    // score = max(esq - (2/s^2)*dot, 0) >= 0 -> raw bits order = float order.
    // 32-bit key = (score_bits & ~0x3F) | (ni*16 | lane&15).
    const int chunk = blockIdx.x * 4 + wn;
    const uint32_t cbase = (uint32_t)(nBase + wn * 64);
    float e4[4];
#pragma unroll
    for (int ni = 0; ni < 4; ++ni) e4[ni] = esq[cbase + ni * 16 + (lane & 15)];
#pragma unroll
    for (int mi = 0; mi < 8; ++mi) {
#pragma unroll
        for (int reg = 0; reg < 4; ++reg) {
            uint32_t p[4];
#pragma unroll
            for (int ni = 0; ni < 4; ++ni) {
                float s = fmaxf(fmaf(-SC2, (float)acc[mi][ni][reg], e4[ni]), 0.f);
                p[ni] = (__float_as_uint(s) & 0xFFFFFFC0u) |
                        (uint32_t)(ni * 16 + (lane & 15));
            }
            mm2u(p[0], p[1]); mm2u(p[2], p[3]);
            merge2u(p[0], p[1], p[2], p[3]);
            uint32_t t1 = p[0], t2 = p[1];
            // DPP rotate-merge within the 16-lane row (disjoint windows 1,2,4,8)
            { uint32_t o1 = rot16<0x121>(t1), o2 = rot16<0x121>(t2);
              merge2u(t1, t2, o1, o2); }
            { uint32_t o1 = rot16<0x122>(t1), o2 = rot16<0x122>(t2);
              merge2u(t1, t2, o1, o2); }
            { uint32_t o1 = rot16<0x124>(t1), o2 = rot16<0x124>(t2);
              merge2u(t1, t2, o1, o2); }
            { uint32_t o1 = rot16<0x128>(t1), o2 = rot16<0x128>(t2);
              merge2u(t1, t2, o1, o2); }
            if ((lane & 15) == 0) {
                const int t = mBase + wm * 128 + mi * 16 + (lane >> 4) * 4 + reg;
                cand[(size_t)t * NCAND + chunk * 2 + 0] =
                    ((u64)(t1 & 0xFFFFFFC0u) << 32) | (cbase + (t1 & 63u));
                cand[(size_t)t * NCAND + chunk * 2 + 1] =
                    ((u64)(t2 & 0xFFFFFFC0u) << 32) | (cbase + (t2 & 63u));
            }
        }
    }
}

// ---------- fused select(top-4) + exact rescore + gather ----------
// grid Mm/8 = 512, 512 threads = 8 waves; wave w owns token t = bx*8 + w.
// Select+rescore: r17 wave-per-token code (HW-verified r11 bench, absmax 0.0).
// Then the block's 8 tokens (same b, consecutive n0..n0+7) are gathered
// cooperatively: thread td handles d = td, td+512; reads values[row_j][d]
// (coalesced across threads per row) and writes out[b][d][n0..n0+7] as two
// float4s (32B contiguous per thread). Saves the gather launch + fidx trip.
__global__ __launch_bounds__(512) void selgather_kernel(const u64* __restrict__ cand,
                                                        const float* __restrict__ xT,
                                                        const float* __restrict__ cb,
                                                        const float* __restrict__ esq,
                                                        const float* __restrict__ values,
                                                        float* __restrict__ out) {
    __shared__ int rows[8];
    const int tid = threadIdx.x, lane = tid & 63, w = tid >> 6;
    const int t = blockIdx.x * 8 + w;
    const u64* cp = cand + (size_t)t * NCAND;
    u64 c0 = cp[lane], c1 = cp[lane + 64], c2 = cp[lane + 128], c3 = cp[lane + 192];
    int cs[4];
#pragma unroll
    for (int rd = 0; rd < 4; ++rd) {
        u64 a01 = c0 < c1 ? c0 : c1;
        u64 a23 = c2 < c3 ? c2 : c3;
        u64 m = a01 < a23 ? a01 : a23;
        { u64 o = rot16_64<0x121>(m); m = m < o ? m : o; }
        { u64 o = rot16_64<0x122>(m); m = m < o ? m : o; }
        { u64 o = rot16_64<0x124>(m); m = m < o ? m : o; }
        { u64 o = rot16_64<0x128>(m); m = m < o ? m : o; }
        { u64 o = __shfl_xor(m, 16, 64); m = m < o ? m : o; }
        { u64 o = __shfl_xor(m, 32, 64); m = m < o ? m : o; }
        cs[rd] = (int)(uint32_t)m;            // wave-uniform
        if (c0 == m) c0 = ~0ULL;              // keys unique per token
        else if (c1 == m) c1 = ~0ULL;
        else if (c2 == m) c2 = ~0ULL;
        else if (c3 == m) c3 = ~0ULL;
    }
    // exact fp32 rescore: 16 floats/lane, 4 coalesced float4 strips
    const float* xrow = xT + (size_t)t * Dd;
    float part[4] = {0.f, 0.f, 0.f, 0.f};
#pragma unroll
    for (int jj = 0; jj < 4; ++jj) {
        const int off = jj * 256 + lane * 4;
        float4 xv = *(const float4*)&xrow[off];
#pragma unroll
        for (int cc = 0; cc < 4; ++cc) {
            float4 wv = *(const float4*)&cb[(size_t)cs[cc] * Dd + off];
            part[cc] += xv.x * wv.x + xv.y * wv.y + xv.z * wv.z + xv.w * wv.w;
        }
    }
#pragma unroll
    for (int cc = 0; cc < 4; ++cc)
#pragma unroll
        for (int off = 1; off < 64; off <<= 1)
            part[cc] += __shfl_xor(part[cc], off, 64);
    if (lane == 0) {
        float bs = 1e30f;
        int bi = 0x7FFFFFFF;
#pragma unroll
        for (int cc = 0; cc < 4; ++cc) {
            float s = fmaf(-2.f, part[cc], esq[cs[cc]]);
            if (s < bs || (s == bs && cs[cc] < bi)) { bs = s; bi = cs[cc]; }
        }
        rows[w] = bi;
    }
    __syncthreads();
    // cooperative gather for the block's 8 tokens (same b, n0..n0+7)
    const int tb = blockIdx.x * 8;
    const int b = tb >> 8, n0 = tb & 255;
    int r[8];
#pragma unroll
    for (int j = 0; j < 8; ++j) r[j] = rows[j];
#pragma unroll
    for (int h = 0; h < 2; ++h) {
        const int d = tid + h * 512;
        float v[8];
#pragma unroll
        for (int j = 0; j < 8; ++j) v[j] = values[(size_t)r[j] * Dd + d];
        float4* dst = (float4*)&out[((size_t)b * Dd + d) * Nn + n0];
        float4 lo, hi;
        lo.x = v[0]; lo.y = v[1]; lo.z = v[2]; lo.w = v[3];
        hi.x = v[4]; hi.y = v[5]; hi.z = v[6]; hi.w = v[7];
        dst[0] = lo;
        dst[1] = hi;
    }
}

extern "C" void kernel_launch(void* const* d_in, const int* in_sizes, int n_in,
                              void* d_out, int out_size, void* d_ws, size_t ws_size,
                              hipStream_t stream) {
    const float* x = (const float*)d_in[0];
    const float* cb = (const float*)d_in[1];
    const float* vals = (const float*)d_in[2];
    float* out = (float*)d_out;

    // ws: [Apk 4M][Bpk 8M][pad->16M][esq 32K][cand 8M][fidx 16K] = 24.28 MB.
    // bigws: xT gets its own 16 MB after that (40.3 MB) and prep fills it;
    // else xT aliases the first 16 MB and is filled post-dist by transx.
    char* p = (char*)d_ws;
    uchar* Apk = (uchar*)p;
    uchar* Bpk = (uchar*)(p + ((size_t)4 << 20));
    float* esq = (float*)(p + ((size_t)16 << 20));
    u64* cand = (u64*)(p + ((size_t)16 << 20) + Kk * 4);
    const size_t base = ((size_t)16 << 20) + Kk * 4 + (size_t)Mm * NCAND * 8 + Mm * 4;
    const bool bigws = ws_size >= base + ((size_t)16 << 20);
    float* xT = bigws ? (float*)(p + base) : (float*)d_ws;

    prep_kernel<<<1024, 256, 0, stream>>>(x, cb, Apk, Bpk, esq,
                                          bigws ? xT : nullptr);
    mfma_dist_kernel<<<dim3(32, 16), 512, 0, stream>>>(Apk, Bpk, esq, cand);
    if (!bigws) transx_kernel<<<dim3(Bb, 32), 256, 0, stream>>>(x, xT);
    selgather_kernel<<<Mm / 8, 512, 0, stream>>>(cand, xT, cb, esq, vals, out);
}

// Round 13
// 171.276 us; speedup vs baseline: 1.0041x; 1.0041x over previous
//
#include <hip/hip_runtime.h>
#include <cstdint>

// VectorQuantizer: x[16,1024,16,16] f32, codebook[1,8192,1024], values[1,8192,1024]
// Round 20 (r19 HW: passed, absmax 0.0, total 172.0 us, dist 47.2 (noise band
// 44-47), launch-fusion NEUTRAL -> tail is real kernel time at low occupancy,
// not launch overhead). This round: dist occupancy-tier fix. Per-wave tile
// 128x64 -> 64x64 (16 waves, 1024 threads): acc 128->64 VGPR, frags 48->32;
// __launch_bounds__(1024,4) targets <=128 VGPR/wave -> 4 waves/SIMD (2x the
// register-pinned 2/SIMD). Sync schedule, LDS layout, staging volume unchanged
// (HW-verified r15-r19). prep/transx/selgather byte-identical to r19.

constexpr int Dd = 1024;   // feature dim (GEMM K)
constexpr int Nn = 256;    // tokens per batch
constexpr int Bb = 16;     // batch
constexpr int Kk = 8192;   // codes (GEMM N)
constexpr int Mm = 4096;   // tokens (GEMM M)
constexpr int STAGES = Dd / 64;     // 16 x 64B K-chunks (kb index)
constexpr int NITER = STAGES / 2;   // 8 main-loop iterations, 128B K per iter
constexpr int NCHUNK = Kk / 64;     // 128 chunks of 64 codes
constexpr int NCAND = NCHUNK * 2;   // 256 candidates per token
constexpr float QS = 24.0f;         // quant scale
constexpr float SC2 = 2.0f / (QS * QS);

typedef __attribute__((ext_vector_type(4))) int vi4;       // 16 i8 = 4 VGPRs
typedef unsigned long long u64;
typedef unsigned char uchar;

__device__ __forceinline__ void gload16(const void* g, void* l) {
    // async global->LDS; lds dest = wave-uniform base + lane*16 (verified r2-r5)
    __builtin_amdgcn_global_load_lds((const __attribute__((address_space(1))) uint32_t*)g,
                                     (__attribute__((address_space(3))) uint32_t*)l, 16, 0, 0);
}

// DPP row_ror:N within 16-lane rows (VALU-rate cross-lane; all lanes active).
template <int CTRL>
__device__ __forceinline__ uint32_t rot16(uint32_t v) {
    return (uint32_t)__builtin_amdgcn_update_dpp(0, (int)v, CTRL, 0xF, 0xF, true);
}
template <int CTRL>
__device__ __forceinline__ u64 rot16_64(u64 v) {
    uint32_t lo = rot16<CTRL>((uint32_t)v);
    uint32_t hi = rot16<CTRL>((uint32_t)(v >> 32));
    return ((u64)hi << 32) | lo;
}

__device__ __forceinline__ void mm2u(uint32_t& a, uint32_t& b) {  // sort pair asc
    uint32_t lo = a < b ? a : b;
    uint32_t hi = a < b ? b : a;
    a = lo; b = hi;
}
// merge sorted pairs: (a1,a2) <- top-2 (smallest) of {a1,a2,b1,b2}
__device__ __forceinline__ void merge2u(uint32_t& a1, uint32_t& a2, uint32_t b1,
                                        uint32_t b2) {
    uint32_t t1 = a1 < b1 ? a1 : b1;
    uint32_t hi = a1 < b1 ? b1 : a1;
    uint32_t l2 = a2 < b2 ? a2 : b2;
    a2 = hi < l2 ? hi : l2;
    a1 = t1;
}

__device__ __forceinline__ int q8(float v) {  // round-to-nearest, clamp [-127,127]
    int qi = (int)rintf(v * QS);
    qi = qi > 127 ? 127 : (qi < -127 ? -127 : qi);
    return qi & 0xFF;
}
__device__ __forceinline__ int pk4i(float a, float b, float c, float d) {
    return q8(a) | (q8(b) << 8) | (q8(c) << 16) | (q8(d) << 24);
}

// Fragment-order packed layout (A and B identical; verified-symmetric for the
// 16x16 family): P[(g*16 + kb)*64 + lane]*16B, g = row>>4, kb = k>>6,
// lane = (row&15) | (q<<4), q = (k>>4)&3, byte j = k&15.

// ---------- prep ----------
// grid 1024: [0,512) cb->Bpk + esq; [512,1024) x->Apk (+xT when non-null)
__global__ __launch_bounds__(256) void prep_kernel(const float* __restrict__ x,
                                                   const float* __restrict__ cb,
                                                   uchar* __restrict__ Apk,
                                                   uchar* __restrict__ Bpk,
                                                   float* __restrict__ esq,
                                                   float* __restrict__ xT) {
    const int tid = threadIdx.x;
    if (blockIdx.x < 512) {  // codebook: 16 codes/block; thread=(rl 4b hi, seg 4b lo)
        const int rl = tid >> 4, seg = tid & 15;   // seg == kb
        const int code = blockIdx.x * 16 + rl;
        const float* src = cb + (size_t)code * Dd + seg * 64;
        float v[64];
        float ss = 0.f;
#pragma unroll
        for (int j = 0; j < 64; j += 4) {
            float4 f = *(const float4*)&src[j];
            v[j] = f.x; v[j + 1] = f.y; v[j + 2] = f.z; v[j + 3] = f.w;
            ss += f.x * f.x + f.y * f.y + f.z * f.z + f.w * f.w;
        }
#pragma unroll
        for (int off = 8; off; off >>= 1) ss += __shfl_down(ss, off, 16);
        if (seg == 0) esq[code] = ss;
        const int g = code >> 4, rlane = code & 15;
#pragma unroll
        for (int q = 0; q < 4; ++q) {
            int o[4];
#pragma unroll
            for (int w4 = 0; w4 < 4; ++w4) {
                const int j = q * 16 + w4 * 4;
                o[w4] = pk4i(v[j], v[j + 1], v[j + 2], v[j + 3]);
            }
            *(uint4*)&Bpk[((size_t)(g * 16 + seg) * 64 + (rlane | (q << 4))) * 16] =
                *(const uint4*)o;
        }
    } else {  // x -> Apk (+ xT): block=(b, d-chunk of 32), thread=n
        const int bb = blockIdx.x - 512;
        const int b = bb >> 5, d0 = (bb & 31) * 32, n = tid;
        const int t = b * 256 + n;
        const float* xb = x + (size_t)b * Dd * Nn + n;
        const int g = t >> 4, rlane = t & 15, kb = d0 >> 6, qbase = (d0 & 32) >> 4;
        float v[32];
#pragma unroll
        for (int jj = 0; jj < 32; ++jj) v[jj] = xb[(size_t)(d0 + jj) * Nn];
#pragma unroll
        for (int h = 0; h < 2; ++h) {
            int o[4];
#pragma unroll
            for (int w4 = 0; w4 < 4; ++w4) {
                const int j = h * 16 + w4 * 4;
                o[w4] = pk4i(v[j], v[j + 1], v[j + 2], v[j + 3]);
            }
            *(uint4*)&Apk[((size_t)(g * 16 + kb) * 64 + (rlane | ((qbase + h) << 4))) * 16] =
                *(const uint4*)o;
        }
        if (xT) {  // bigws only: write the already-loaded slice to xT
            float* row = xT + (size_t)t * Dd + d0;
#pragma unroll
            for (int jj = 0; jj < 32; jj += 4) {
                float4 f;
                f.x = v[jj]; f.y = v[jj + 1]; f.z = v[jj + 2]; f.w = v[jj + 3];
                *(float4*)&row[jj] = f;
            }
        }
    }
}

// ---------- x -> xT fp32 (fallback path, AFTER dist; aliases Apk/Bpk region) ----------
__global__ __launch_bounds__(256) void transx_kernel(const float* __restrict__ x,
                                                     float* __restrict__ xT) {
    const int n = threadIdx.x, b = blockIdx.x, d0 = blockIdx.y * 32;
    const float* xb = x + (size_t)b * Dd * Nn + n;
    float* row = xT + (size_t)(b * Nn + n) * Dd + d0;
#pragma unroll
    for (int jj = 0; jj < 8; ++jj) {
        float4 v;
        v.x = xb[(size_t)(d0 + jj * 4 + 0) * Nn];
        v.y = xb[(size_t)(d0 + jj * 4 + 1) * Nn];
        v.z = xb[(size_t)(d0 + jj * 4 + 2) * Nn];
        v.w = xb[(size_t)(d0 + jj * 4 + 3) * Nn];
        *(float4*)&row[jj * 4] = v;
    }
}

// ---------- i8 MFMA distance: 256x256 tile, 16 waves x 64x64, 4 waves/SIMD ----
// grid (32, 16), 1024 threads = 16 waves (wm = w>>2 in [0,4), wn = w&3 in [0,4)).
// Wave owns a 64x64 output tile = 4x4 fragments of 16x16x64 MFMA -> acc 64 VGPR
// (+32 frag) fits the <=128 tier: 4 waves/SIMD, double the old occupancy.
// LDS unchanged: dbuf x 2 kt x 16 groups x 1KB for A and B = 128 KB (1 blk/CU).
// Main loop: 8 iters, 128B K each, ONE barrier per iter (schedule = r15-r19):
//   vmcnt(0) -> s_barrier -> sched_barrier(0) -> stage iter i+1 (4 gloads/wave,
//   waves 0-7 stage A groups 2w,2w+1; waves 8-15 stage B) -> 16 ds_read_b128 +
//   32 MFMA under setprio(1).
__global__ __launch_bounds__(1024, 4) void mfma_dist_kernel(const uchar* __restrict__ Apk,
                                                            const uchar* __restrict__ Bpk,
                                                            const float* __restrict__ esq,
                                                            u64* __restrict__ cand) {
    __shared__ uchar As[2 * 2 * 16 * 1024];  // [buf][kt][group][1KB]
    __shared__ uchar Bs[2 * 2 * 16 * 1024];

    const int tid = threadIdx.x, lane = tid & 63, w = tid >> 6;
    const int wm = w >> 2, wn = w & 3;
    const int nBase = blockIdx.x * 256, mBase = blockIdx.y * 256;
    const int gA = blockIdx.y * 16, gB = blockIdx.x * 16;  // global 16-row group bases

    vi4 acc[4][4];
#pragma unroll
    for (int i = 0; i < 4; ++i)
#pragma unroll
        for (int j = 0; j < 4; ++j) acc[i][j] = (vi4)0;

    // Staging: waves 0-7 stage A groups 2w, 2w+1; waves 8-15 stage B likewise.
    const bool isA = (w < 8);
    const uchar* gmat = isA ? Apk : Bpk;
    const int gBase = (isA ? gA : gB) + (w & 7) * 2;
    const uchar* gsrc = gmat + (size_t)gBase * 16384 + (size_t)lane * 16;
    uchar* swave = (isA ? As : Bs) + (w & 7) * 2048;  // + buf*32768 + kt*16384 + r*1024

    // issue both kt sub-tiles of iteration it into buffer buf (2 groups/wave)
    auto stage_iter = [&](int buf, int it) {
#pragma unroll
        for (int kt = 0; kt < 2; ++kt) {
            const int kb = 2 * it + kt;
            uchar* ldst = swave + buf * 32768 + kt * 16384;
#pragma unroll
            for (int r = 0; r < 2; ++r)
                gload16(gsrc + (size_t)(r * 16 + kb) * 1024, ldst + r * 1024);
        }
    };

    auto compute = [&](int buf, int kt) {
        const uchar* ab = As + buf * 32768 + kt * 16384;
        const uchar* bb = Bs + buf * 32768 + kt * 16384;
        vi4 af[4], bf[4];
#pragma unroll
        for (int mi = 0; mi < 4; ++mi)
            af[mi] = *(const vi4*)&ab[((wm * 4 + mi) * 64 + lane) * 16];
#pragma unroll
        for (int ni = 0; ni < 4; ++ni)
            bf[ni] = *(const vi4*)&bb[((wn * 4 + ni) * 64 + lane) * 16];
#pragma unroll
        for (int mi = 0; mi < 4; ++mi)
#pragma unroll
            for (int ni = 0; ni < 4; ++ni)
                acc[mi][ni] = __builtin_amdgcn_mfma_i32_16x16x64_i8(
                    af[mi], bf[ni], acc[mi][ni], 0, 0, 0);
    };

    // prologue: stage iter 0 into buf 0
    stage_iter(0, 0);

    for (int i = 0; i < NITER; ++i) {
        const int buf = i & 1;
        asm volatile("s_waitcnt vmcnt(0)" ::: "memory");  // iter i's loads done
        __builtin_amdgcn_s_barrier();                     // publish to all waves
        __builtin_amdgcn_sched_barrier(0);                // pin everything below
        if (i + 1 < NITER) stage_iter(buf ^ 1, i + 1);    // post-barrier: WAR-safe
        __builtin_amdgcn_s_setprio(1);
        compute(buf, 0);
        compute(buf, 1);
        __builtin_amdgcn_s_setprio(0);
    }

    // Epilogue. C/D: col = lane&15 (+ni*16), row = (lane>>4)*4 + reg.
    // score = max(esq - (2/s^2)*dot, 0) >= 0 -> raw bits order = float order.
    // 32-bit key = (score_bits & ~0x3F) | (ni*16 | lane&15).
    // Wave rows: mBase + wm*64 + mi*16 + (lane>>4)*4 + reg; cols: chunk wn.
    const int chunk = blockIdx.x * 4 + wn;
    const uint32_t cbase = (uint32_t)(nBase + wn * 64);
    float e4[4];
#pragma unroll
    for (int ni = 0; ni < 4; ++ni) e4[ni] = esq[cbase + ni * 16 + (lane & 15)];
#pragma unroll
    for (int mi = 0; mi < 4; ++mi) {
#pragma unroll
        for (int reg = 0; reg < 4; ++reg) {
            uint32_t p[4];
#pragma unroll
            for (int ni = 0; ni < 4; ++ni) {
                float s = fmaxf(fmaf(-SC2, (float)acc[mi][ni][reg], e4[ni]), 0.f);
                p[ni] = (__float_as_uint(s) & 0xFFFFFFC0u) |
                        (uint32_t)(ni * 16 + (lane & 15));
            }
            mm2u(p[0], p[1]); mm2u(p[2], p[3]);
            merge2u(p[0], p[1], p[2], p[3]);
            uint32_t t1 = p[0], t2 = p[1];
            // DPP rotate-merge within the 16-lane row (disjoint windows 1,2,4,8)
            { uint32_t o1 = rot16<0x121>(t1), o2 = rot16<0x121>(t2);
              merge2u(t1, t2, o1, o2); }
            { uint32_t o1 = rot16<0x122>(t1), o2 = rot16<0x122>(t2);
              merge2u(t1, t2, o1, o2); }
            { uint32_t o1 = rot16<0x124>(t1), o2 = rot16<0x124>(t2);
              merge2u(t1, t2, o1, o2); }
            { uint32_t o1 = rot16<0x128>(t1), o2 = rot16<0x128>(t2);
              merge2u(t1, t2, o1, o2); }
            if ((lane & 15) == 0) {
                const int t = mBase + wm * 64 + mi * 16 + (lane >> 4) * 4 + reg;
                cand[(size_t)t * NCAND + chunk * 2 + 0] =
                    ((u64)(t1 & 0xFFFFFFC0u) << 32) | (cbase + (t1 & 63u));
                cand[(size_t)t * NCAND + chunk * 2 + 1] =
                    ((u64)(t2 & 0xFFFFFFC0u) << 32) | (cbase + (t2 & 63u));
            }
        }
    }
}

// ---------- fused select(top-4) + exact rescore + gather ----------
// grid Mm/8 = 512, 512 threads = 8 waves; wave w owns token t = bx*8 + w.
// Select+rescore: r17 wave-per-token code (HW-verified, absmax 0.0). Then the
// block's 8 tokens (same b, consecutive n0..n0+7) are gathered cooperatively.
__global__ __launch_bounds__(512) void selgather_kernel(const u64* __restrict__ cand,
                                                        const float* __restrict__ xT,
                                                        const float* __restrict__ cb,
                                                        const float* __restrict__ esq,
                                                        const float* __restrict__ values,
                                                        float* __restrict__ out) {
    __shared__ int rows[8];
    const int tid = threadIdx.x, lane = tid & 63, w = tid >> 6;
    const int t = blockIdx.x * 8 + w;
    const u64* cp = cand + (size_t)t * NCAND;
    u64 c0 = cp[lane], c1 = cp[lane + 64], c2 = cp[lane + 128], c3 = cp[lane + 192];
    int cs[4];
#pragma unroll
    for (int rd = 0; rd < 4; ++rd) {
        u64 a01 = c0 < c1 ? c0 : c1;
        u64 a23 = c2 < c3 ? c2 : c3;
        u64 m = a01 < a23 ? a01 : a23;
        { u64 o = rot16_64<0x121>(m); m = m < o ? m : o; }
        { u64 o = rot16_64<0x122>(m); m = m < o ? m : o; }
        { u64 o = rot16_64<0x124>(m); m = m < o ? m : o; }
        { u64 o = rot16_64<0x128>(m); m = m < o ? m : o; }
        { u64 o = __shfl_xor(m, 16, 64); m = m < o ? m : o; }
        { u64 o = __shfl_xor(m, 32, 64); m = m < o ? m : o; }
        cs[rd] = (int)(uint32_t)m;            // wave-uniform
        if (c0 == m) c0 = ~0ULL;              // keys unique per token
        else if (c1 == m) c1 = ~0ULL;
        else if (c2 == m) c2 = ~0ULL;
        else if (c3 == m) c3 = ~0ULL;
    }
    // exact fp32 rescore: 16 floats/lane, 4 coalesced float4 strips
    const float* xrow = xT + (size_t)t * Dd;
    float part[4] = {0.f, 0.f, 0.f, 0.f};
#pragma unroll
    for (int jj = 0; jj < 4; ++jj) {
        const int off = jj * 256 + lane * 4;
        float4 xv = *(const float4*)&xrow[off];
#pragma unroll
        for (int cc = 0; cc < 4; ++cc) {
            float4 wv = *(const float4*)&cb[(size_t)cs[cc] * Dd + off];
            part[cc] += xv.x * wv.x + xv.y * wv.y + xv.z * wv.z + xv.w * wv.w;
        }
    }
#pragma unroll
    for (int cc = 0; cc < 4; ++cc)
#pragma unroll
        for (int off = 1; off < 64; off <<= 1)
            part[cc] += __shfl_xor(part[cc], off, 64);
    if (lane == 0) {
        float bs = 1e30f;
        int bi = 0x7FFFFFFF;
#pragma unroll
        for (int cc = 0; cc < 4; ++cc) {
            float s = fmaf(-2.f, part[cc], esq[cs[cc]]);
            if (s < bs || (s == bs && cs[cc] < bi)) { bs = s; bi = cs[cc]; }
        }
        rows[w] = bi;
    }
    __syncthreads();
    // cooperative gather for the block's 8 tokens (same b, n0..n0+7)
    const int tb = blockIdx.x * 8;
    const int b = tb >> 8, n0 = tb & 255;
    int r[8];
#pragma unroll
    for (int j = 0; j < 8; ++j) r[j] = rows[j];
#pragma unroll
    for (int h = 0; h < 2; ++h) {
        const int d = tid + h * 512;
        float v[8];
#pragma unroll
        for (int j = 0; j < 8; ++j) v[j] = values[(size_t)r[j] * Dd + d];
        float4* dst = (float4*)&out[((size_t)b * Dd + d) * Nn + n0];
        float4 lo, hi;
        lo.x = v[0]; lo.y = v[1]; lo.z = v[2]; lo.w = v[3];
        hi.x = v[4]; hi.y = v[5]; hi.z = v[6]; hi.w = v[7];
        dst[0] = lo;
        dst[1] = hi;
    }
}

extern "C" void kernel_launch(void* const* d_in, const int* in_sizes, int n_in,
                              void* d_out, int out_size, void* d_ws, size_t ws_size,
                              hipStream_t stream) {
    const float* x = (const float*)d_in[0];
    const float* cb = (const float*)d_in[1];
    const float* vals = (const float*)d_in[2];
    float* out = (float*)d_out;

    // ws: [Apk 4M][Bpk 8M][pad->16M][esq 32K][cand 8M][fidx 16K] = 24.28 MB.
    // bigws: xT gets its own 16 MB after that (40.3 MB) and prep fills it;
    // else xT aliases the first 16 MB and is filled post-dist by transx.
    char* p = (char*)d_ws;
    uchar* Apk = (uchar*)p;
    uchar* Bpk = (uchar*)(p + ((size_t)4 << 20));
    float* esq = (float*)(p + ((size_t)16 << 20));
    u64* cand = (u64*)(p + ((size_t)16 << 20) + Kk * 4);
    const size_t base = ((size_t)16 << 20) + Kk * 4 + (size_t)Mm * NCAND * 8 + Mm * 4;
    const bool bigws = ws_size >= base + ((size_t)16 << 20);
    float* xT = bigws ? (float*)(p + base) : (float*)d_ws;

    prep_kernel<<<1024, 256, 0, stream>>>(x, cb, Apk, Bpk, esq,
                                          bigws ? xT : nullptr);
    mfma_dist_kernel<<<dim3(32, 16), 1024, 0, stream>>>(Apk, Bpk, esq, cand);
    if (!bigws) transx_kernel<<<dim3(Bb, 32), 256, 0, stream>>>(x, xT);
    selgather_kernel<<<Mm / 8, 512, 0, stream>>>(cand, xT, cb, esq, vals, out);
}